// Round 1
// baseline (312.019 us; speedup 1.0000x reference)
//
#include <hip/hip_runtime.h>
#include <cstdint>

#define HEAT_THRESH 0.1f
#define WW 256
#define HH 256
#define TOPK 30
#define CAP 8192

__device__ __forceinline__ unsigned long long umax64(unsigned long long a, unsigned long long b) {
    return a > b ? a : b;
}

__global__ __launch_bounds__(256, 2) void pose_topk_kernel(const float* __restrict__ heat,
                                                           float* __restrict__ out, int BC) {
    const int bc = blockIdx.x;
    const float* __restrict__ hm = heat + (size_t)bc * (HH * WW);
    const int tid = threadIdx.x;
    const int lane = tid & 63;
    const int cx = tid & 63;   // column group: columns [cx*4, cx*4+4)
    const int ry = tid >> 6;   // row band: rows [ry*64, ry*64+64)

    __shared__ unsigned long long cand[CAP];
    __shared__ int cnt;
    __shared__ unsigned long long wmax[4];
    __shared__ unsigned long long gmax_s;
    __shared__ float out_x[TOPK], out_y[TOPK], out_s[TOPK], out_v[TOPK];

    if (tid == 0) cnt = 0;
    __syncthreads();

    const int x0 = cx * 4;
    const int y0 = ry * 64;
    const float NEG = -INFINITY;

    // load row y: center float4 + left/right halo scalars
    auto loadrow = [&](int y, float4& v, float& l, float& r) {
        const float* row = hm + y * WW + x0;
        v = *reinterpret_cast<const float4*>(row);
        l = (cx > 0) ? row[-1] : NEG;
        r = (cx < 63) ? row[4] : NEG;
    };
    auto hmax4 = [&](const float4& v, float l, float r, float4& h) {
        h.x = fmaxf(fmaxf(l, v.x), v.y);
        h.y = fmaxf(fmaxf(v.x, v.y), v.z);
        h.z = fmaxf(fmaxf(v.y, v.z), v.w);
        h.w = fmaxf(fmaxf(v.z, v.w), r);
    };
    // wave-aggregated candidate push
    auto push = [&](bool isc, float val, int idx) {
        unsigned long long m = __ballot(isc);
        if (m) {
            int leader = __ffsll((unsigned long long)m) - 1;
            int nb = __popcll(m);
            int base = 0;
            if (lane == leader) base = atomicAdd(&cnt, nb);
            base = __shfl(base, leader);
            if (isc) {
                int off = __popcll(m & ((1ull << lane) - 1ull));
                int pos = base + off;
                if (pos < CAP) {
                    unsigned long long fb = (unsigned long long)__float_as_uint(val);
                    cand[pos] = (fb << 32) | (unsigned long long)(0xFFFFu - (unsigned)idx);
                }
            }
        }
    };

    float4 hmA, hmB, cB;
    if (y0 > 0) {
        float4 v; float l, r;
        loadrow(y0 - 1, v, l, r);
        hmax4(v, l, r, hmA);
    } else {
        hmA = make_float4(NEG, NEG, NEG, NEG);
    }
    {
        float4 v; float l, r;
        loadrow(y0, v, l, r);
        cB = v;
        hmax4(v, l, r, hmB);
    }

    for (int t = 0; t < 64; ++t) {
        const int y = y0 + t;
        float4 hmC, cC;
        if (y + 1 < HH) {
            float4 v; float l, r;
            loadrow(y + 1, v, l, r);
            cC = v;
            hmax4(v, l, r, hmC);
        } else {
            hmC = make_float4(NEG, NEG, NEG, NEG);
            cC = hmC;
        }
        // 3x3 window max for row y, 4 columns
        float va0 = fmaxf(fmaxf(hmA.x, hmB.x), hmC.x);
        float va1 = fmaxf(fmaxf(hmA.y, hmB.y), hmC.y);
        float va2 = fmaxf(fmaxf(hmA.z, hmB.z), hmC.z);
        float va3 = fmaxf(fmaxf(hmA.w, hmB.w), hmC.w);
        const int ib = y * WW + x0;
        push((cB.x == va0) && (cB.x > HEAT_THRESH), cB.x, ib + 0);
        push((cB.y == va1) && (cB.y > HEAT_THRESH), cB.y, ib + 1);
        push((cB.z == va2) && (cB.z > HEAT_THRESH), cB.z, ib + 2);
        push((cB.w == va3) && (cB.w > HEAT_THRESH), cB.w, ib + 3);
        hmA = hmB; hmB = hmC; cB = cC;
    }
    __syncthreads();

    const int ncand = min(cnt, CAP);

    // per-thread chunk max (strided chunks)
    unsigned long long lmax = 0ull;
    for (int i = tid; i < ncand; i += 256) lmax = umax64(lmax, cand[i]);

    for (int k = 0; k < TOPK; ++k) {
        // wave max reduce
        unsigned long long wm = lmax;
        #pragma unroll
        for (int s = 32; s; s >>= 1) {
            unsigned long long o = (unsigned long long)__shfl_xor((long long)wm, s, 64);
            wm = umax64(wm, o);
        }
        if (lane == 0) wmax[tid >> 6] = wm;
        __syncthreads();
        if (tid == 0) {
            unsigned long long gm = umax64(umax64(wmax[0], wmax[1]), umax64(wmax[2], wmax[3]));
            gmax_s = gm;
            if (gm != 0ull) {
                unsigned fb = (unsigned)(gm >> 32);
                unsigned idx = 0xFFFFu - (unsigned)(gm & 0xFFFFFFFFull);
                out_x[k] = (float)((idx % WW) * 4);
                out_y[k] = (float)((idx / WW) * 4);
                out_s[k] = __uint_as_float(fb);
                out_v[k] = 1.0f;
            } else {
                out_x[k] = 0.0f; out_y[k] = 0.0f; out_s[k] = 0.0f; out_v[k] = 0.0f;
            }
        }
        __syncthreads();
        const unsigned long long gm = gmax_s;
        if (gm != 0ull && lmax == gm) {
            // winner: remove element and recompute chunk max
            unsigned long long nl = 0ull;
            for (int i = tid; i < ncand; i += 256) {
                if (cand[i] == gm) cand[i] = 0ull;
                nl = umax64(nl, cand[i]);
            }
            lmax = nl;
        }
    }
    __syncthreads();

    if (tid < TOPK) {
        const int k = tid;
        const size_t bk = (size_t)bc * TOPK + k;
        const size_t nbk = (size_t)BC * TOPK;
        out[bk * 2]     = out_x[k];
        out[bk * 2 + 1] = out_y[k];
        out[nbk * 2 + bk] = out_s[k];
        out[nbk * 3 + bk] = out_v[k];
    }
}

extern "C" void kernel_launch(void* const* d_in, const int* in_sizes, int n_in,
                              void* d_out, int out_size, void* d_ws, size_t ws_size,
                              hipStream_t stream) {
    const float* heat = (const float*)d_in[0];
    float* out = (float*)d_out;
    const int BC = in_sizes[0] / (HH * WW);
    hipLaunchKernelGGL(pose_topk_kernel, dim3(BC), dim3(256), 0, stream, heat, out, BC);
}

// Round 2
// 94.018 us; speedup vs baseline: 3.3187x; 3.3187x over previous
//
#include <hip/hip_runtime.h>
#include <cstdint>

#define HEAT_THRESH 0.1f
#define WW 256
#define HH 256
#define TOPK 30
#define NBINS 2048
#define CAP2 1024
#define BASEBITS 0x3DCCCCCDu  /* float bits of 0.1f */
#define BINSH 14
#define MAXBIN 1740           /* ((0x3F800000 - BASEBITS) >> 14) */

__device__ __forceinline__ unsigned long long umax64(unsigned long long a, unsigned long long b) {
    return a > b ? a : b;
}

__global__ __launch_bounds__(256, 4) void pose_topk_kernel(const float* __restrict__ heat,
                                                           float* __restrict__ out, int BC) {
    const int bc = blockIdx.x;
    const float* __restrict__ hm = heat + (size_t)bc * (HH * WW);
    const int tid = threadIdx.x;
    const int lane = tid & 63;
    const int cx = tid & 63;   // column group: columns [cx*4, cx*4+4)
    const int ry = tid >> 6;   // row band: rows [ry*64, ry*64+64)

    __shared__ unsigned int hist[NBINS];
    __shared__ unsigned long long cand[CAP2];
    __shared__ int cnt;
    __shared__ unsigned int tbbits_s;

    #pragma unroll
    for (int i = 0; i < NBINS / 256; ++i) hist[tid + 256 * i] = 0u;
    if (tid == 0) cnt = 0;
    __syncthreads();

    const int x0 = cx * 4;
    const int y0 = ry * 64;
    const float NEG = -INFINITY;

    auto loadrow = [&](int y, float4& v, float& l, float& r) {
        const float* row = hm + y * WW + x0;
        v = *reinterpret_cast<const float4*>(row);
        l = (cx > 0) ? row[-1] : NEG;
        r = (cx < 63) ? row[4] : NEG;
    };
    auto hmax4 = [&](const float4& v, float l, float r, float4& h) {
        h.x = fmaxf(fmaxf(l, v.x), v.y);
        h.y = fmaxf(fmaxf(v.x, v.y), v.z);
        h.z = fmaxf(fmaxf(v.y, v.z), v.w);
        h.w = fmaxf(fmaxf(v.z, v.w), r);
    };

    // ---------- Pass A: NMS + value histogram ----------
    {
        float4 hmA, hmB, cB;
        if (y0 > 0) { float4 v; float l, r; loadrow(y0 - 1, v, l, r); hmax4(v, l, r, hmA); }
        else hmA = make_float4(NEG, NEG, NEG, NEG);
        { float4 v; float l, r; loadrow(y0, v, l, r); cB = v; hmax4(v, l, r, hmB); }

        for (int t = 0; t < 64; ++t) {
            const int y = y0 + t;
            float4 hmC, cC;
            if (y + 1 < HH) { float4 v; float l, r; loadrow(y + 1, v, l, r); cC = v; hmax4(v, l, r, hmC); }
            else { hmC = make_float4(NEG, NEG, NEG, NEG); cC = hmC; }
            float va0 = fmaxf(fmaxf(hmA.x, hmB.x), hmC.x);
            float va1 = fmaxf(fmaxf(hmA.y, hmB.y), hmC.y);
            float va2 = fmaxf(fmaxf(hmA.z, hmB.z), hmC.z);
            float va3 = fmaxf(fmaxf(hmA.w, hmB.w), hmC.w);
            if (cB.x == va0 && cB.x > HEAT_THRESH) atomicAdd(&hist[(__float_as_uint(cB.x) - BASEBITS) >> BINSH], 1u);
            if (cB.y == va1 && cB.y > HEAT_THRESH) atomicAdd(&hist[(__float_as_uint(cB.y) - BASEBITS) >> BINSH], 1u);
            if (cB.z == va2 && cB.z > HEAT_THRESH) atomicAdd(&hist[(__float_as_uint(cB.z) - BASEBITS) >> BINSH], 1u);
            if (cB.w == va3 && cB.w > HEAT_THRESH) atomicAdd(&hist[(__float_as_uint(cB.w) - BASEBITS) >> BINSH], 1u);
            hmA = hmB; hmB = hmC; cB = cC;
        }
    }
    __syncthreads();

    // ---------- Threshold-bin scan (thread 0; exits in ~2-3 iters: values crowd near 1.0) ----------
    if (tid == 0) {
        unsigned cum = 0;
        int b;
        for (b = MAXBIN; b >= 0; --b) {
            cum += hist[b];
            if (cum >= TOPK) break;
        }
        if (b < 0) b = 0;
        tbbits_s = BASEBITS + ((unsigned)b << BINSH);
    }
    __syncthreads();
    const unsigned tbbits = tbbits_s;

    // ---------- Pass B: collect candidates >= threshold bin (~60-130 per slice) ----------
    {
        float4 hmA, hmB, cB;
        if (y0 > 0) { float4 v; float l, r; loadrow(y0 - 1, v, l, r); hmax4(v, l, r, hmA); }
        else hmA = make_float4(NEG, NEG, NEG, NEG);
        { float4 v; float l, r; loadrow(y0, v, l, r); cB = v; hmax4(v, l, r, hmB); }

        for (int t = 0; t < 64; ++t) {
            const int y = y0 + t;
            float4 hmC, cC;
            if (y + 1 < HH) { float4 v; float l, r; loadrow(y + 1, v, l, r); cC = v; hmax4(v, l, r, hmC); }
            else { hmC = make_float4(NEG, NEG, NEG, NEG); cC = hmC; }
            float va0 = fmaxf(fmaxf(hmA.x, hmB.x), hmC.x);
            float va1 = fmaxf(fmaxf(hmA.y, hmB.y), hmC.y);
            float va2 = fmaxf(fmaxf(hmA.z, hmB.z), hmC.z);
            float va3 = fmaxf(fmaxf(hmA.w, hmB.w), hmC.w);
            const int ib = y * WW + x0;
            #define TRYPUSH(c, va, off)                                                          \
                if ((c) == (va) && (c) > HEAT_THRESH && __float_as_uint(c) >= tbbits) {          \
                    int pos = atomicAdd(&cnt, 1);                                                \
                    if (pos < CAP2) {                                                            \
                        unsigned long long fb = (unsigned long long)__float_as_uint(c);          \
                        cand[pos] = (fb << 32) | (unsigned long long)(0xFFFFu - (unsigned)(ib + (off))); \
                    }                                                                            \
                }
            TRYPUSH(cB.x, va0, 0)
            TRYPUSH(cB.y, va1, 1)
            TRYPUSH(cB.z, va2, 2)
            TRYPUSH(cB.w, va3, 3)
            #undef TRYPUSH
            hmA = hmB; hmB = hmC; cB = cC;
        }
    }
    __syncthreads();

    // ---------- Single-wave top-30 selection (no barriers) ----------
    if (tid < 64) {
        const int n = min(cnt, CAP2);
        unsigned long long lmax = 0ull;
        for (int i = lane; i < n; i += 64) lmax = umax64(lmax, cand[i]);

        for (int k = 0; k < TOPK; ++k) {
            unsigned long long wm = lmax;
            #pragma unroll
            for (int s = 32; s; s >>= 1) {
                unsigned long long o = (unsigned long long)__shfl_xor((long long)wm, s, 64);
                wm = umax64(wm, o);
            }
            const unsigned long long gm = wm;  // all lanes agree
            if (lane == 0) {
                const size_t bk = (size_t)bc * TOPK + k;
                const size_t nbk = (size_t)BC * TOPK;
                if (gm != 0ull) {
                    unsigned fb = (unsigned)(gm >> 32);
                    unsigned idx = 0xFFFFu - (unsigned)(gm & 0xFFFFFFFFull);
                    out[bk * 2]       = (float)((idx % WW) * 4);
                    out[bk * 2 + 1]   = (float)((idx / WW) * 4);
                    out[nbk * 2 + bk] = __uint_as_float(fb);
                    out[nbk * 3 + bk] = 1.0f;
                } else {
                    out[bk * 2] = 0.0f; out[bk * 2 + 1] = 0.0f;
                    out[nbk * 2 + bk] = 0.0f; out[nbk * 3 + bk] = 0.0f;
                }
            }
            if (gm != 0ull && lmax == gm) {
                unsigned long long nl = 0ull;
                for (int i = lane; i < n; i += 64) {
                    if (cand[i] == gm) cand[i] = 0ull;
                    nl = umax64(nl, cand[i]);
                }
                lmax = nl;
            }
        }
    }
}

extern "C" void kernel_launch(void* const* d_in, const int* in_sizes, int n_in,
                              void* d_out, int out_size, void* d_ws, size_t ws_size,
                              hipStream_t stream) {
    const float* heat = (const float*)d_in[0];
    float* out = (float*)d_out;
    const int BC = in_sizes[0] / (HH * WW);
    hipLaunchKernelGGL(pose_topk_kernel, dim3(BC), dim3(256), 0, stream, heat, out, BC);
}

// Round 3
// 92.467 us; speedup vs baseline: 3.3744x; 1.0168x over previous
//
#include <hip/hip_runtime.h>
#include <cstdint>

#define HEAT_THRESH 0.1f
#define WW 256
#define HH 256
#define TOPK 30
#define NBINS 2048
#define CAP2 1024
#define BASEBITS 0x3DCCCCCDu  /* float bits of 0.1f */
#define BINSH 14
#define MAXBIN 1740           /* ((0x3F800000 - BASEBITS) >> 14) */

__device__ __forceinline__ unsigned long long umax64(unsigned long long a, unsigned long long b) {
    return a > b ? a : b;
}

__global__ __launch_bounds__(1024, 2) void pose_topk_kernel(const float* __restrict__ heat,
                                                            float* __restrict__ out, int BC) {
    const int bc = blockIdx.x;
    const float* __restrict__ hm = heat + (size_t)bc * (HH * WW);
    const int tid = threadIdx.x;
    const int lane = tid & 63;
    const int cx = tid & 63;   // column group: columns [cx*4, cx*4+4)
    const int ry = tid >> 6;   // row band: rows [ry*16, ry*16+16)  (16 bands)

    __shared__ unsigned int hist[NBINS];
    __shared__ unsigned long long cand[CAP2];
    __shared__ int cnt;
    __shared__ unsigned int tbbits_s;

    hist[tid & (NBINS - 1)] = 0u;          // 1024 threads cover 2048 bins in 2 writes
    hist[(tid + 1024) & (NBINS - 1)] = 0u;
    if (tid == 0) cnt = 0;
    __syncthreads();

    const int x0 = cx * 4;
    const int y0 = ry * 16;
    const float NEG = -INFINITY;

    auto loadrow = [&](int y, float4& v, float& l, float& r) {
        const float* row = hm + y * WW + x0;
        v = *reinterpret_cast<const float4*>(row);
        l = (cx > 0) ? row[-1] : NEG;
        r = (cx < 63) ? row[4] : NEG;
    };
    auto hmax4 = [&](const float4& v, float l, float r, float4& h) {
        h.x = fmaxf(fmaxf(l, v.x), v.y);
        h.y = fmaxf(fmaxf(v.x, v.y), v.z);
        h.z = fmaxf(fmaxf(v.y, v.z), v.w);
        h.w = fmaxf(fmaxf(v.z, v.w), r);
    };

    // ---------- Pass A: NMS + value histogram ----------
    {
        float4 hmA, hmB, cB;
        if (y0 > 0) { float4 v; float l, r; loadrow(y0 - 1, v, l, r); hmax4(v, l, r, hmA); }
        else hmA = make_float4(NEG, NEG, NEG, NEG);
        { float4 v; float l, r; loadrow(y0, v, l, r); cB = v; hmax4(v, l, r, hmB); }

        for (int t = 0; t < 16; ++t) {
            const int y = y0 + t;
            float4 hmC, cC;
            if (y + 1 < HH) { float4 v; float l, r; loadrow(y + 1, v, l, r); cC = v; hmax4(v, l, r, hmC); }
            else { hmC = make_float4(NEG, NEG, NEG, NEG); cC = hmC; }
            float va0 = fmaxf(fmaxf(hmA.x, hmB.x), hmC.x);
            float va1 = fmaxf(fmaxf(hmA.y, hmB.y), hmC.y);
            float va2 = fmaxf(fmaxf(hmA.z, hmB.z), hmC.z);
            float va3 = fmaxf(fmaxf(hmA.w, hmB.w), hmC.w);
            if (cB.x == va0 && cB.x > HEAT_THRESH) atomicAdd(&hist[(__float_as_uint(cB.x) - BASEBITS) >> BINSH], 1u);
            if (cB.y == va1 && cB.y > HEAT_THRESH) atomicAdd(&hist[(__float_as_uint(cB.y) - BASEBITS) >> BINSH], 1u);
            if (cB.z == va2 && cB.z > HEAT_THRESH) atomicAdd(&hist[(__float_as_uint(cB.z) - BASEBITS) >> BINSH], 1u);
            if (cB.w == va3 && cB.w > HEAT_THRESH) atomicAdd(&hist[(__float_as_uint(cB.w) - BASEBITS) >> BINSH], 1u);
            hmA = hmB; hmB = hmC; cB = cC;
        }
    }
    __syncthreads();

    // ---------- Threshold-bin scan (thread 0; exits in ~2-3 iters: values crowd near 1.0) ----------
    if (tid == 0) {
        unsigned cum = 0;
        int b;
        for (b = MAXBIN; b >= 0; --b) {
            cum += hist[b];
            if (cum >= TOPK) break;
        }
        if (b < 0) b = 0;
        tbbits_s = BASEBITS + ((unsigned)b << BINSH);
    }
    __syncthreads();
    const unsigned tbbits = tbbits_s;

    // ---------- Pass B: collect candidates >= threshold bin (~60-130 per slice) ----------
    {
        float4 hmA, hmB, cB;
        if (y0 > 0) { float4 v; float l, r; loadrow(y0 - 1, v, l, r); hmax4(v, l, r, hmA); }
        else hmA = make_float4(NEG, NEG, NEG, NEG);
        { float4 v; float l, r; loadrow(y0, v, l, r); cB = v; hmax4(v, l, r, hmB); }

        for (int t = 0; t < 16; ++t) {
            const int y = y0 + t;
            float4 hmC, cC;
            if (y + 1 < HH) { float4 v; float l, r; loadrow(y + 1, v, l, r); cC = v; hmax4(v, l, r, hmC); }
            else { hmC = make_float4(NEG, NEG, NEG, NEG); cC = hmC; }
            float va0 = fmaxf(fmaxf(hmA.x, hmB.x), hmC.x);
            float va1 = fmaxf(fmaxf(hmA.y, hmB.y), hmC.y);
            float va2 = fmaxf(fmaxf(hmA.z, hmB.z), hmC.z);
            float va3 = fmaxf(fmaxf(hmA.w, hmB.w), hmC.w);
            const int ib = y * WW + x0;
            #define TRYPUSH(c, va, off)                                                          \
                if ((c) == (va) && (c) > HEAT_THRESH && __float_as_uint(c) >= tbbits) {          \
                    int pos = atomicAdd(&cnt, 1);                                                \
                    if (pos < CAP2) {                                                            \
                        unsigned long long fb = (unsigned long long)__float_as_uint(c);          \
                        cand[pos] = (fb << 32) | (unsigned long long)(0xFFFFu - (unsigned)(ib + (off))); \
                    }                                                                            \
                }
            TRYPUSH(cB.x, va0, 0)
            TRYPUSH(cB.y, va1, 1)
            TRYPUSH(cB.z, va2, 2)
            TRYPUSH(cB.w, va3, 3)
            #undef TRYPUSH
            hmA = hmB; hmB = hmC; cB = cC;
        }
    }
    __syncthreads();

    // ---------- Single-wave top-30 selection (no barriers) ----------
    if (tid < 64) {
        const int n = min(cnt, CAP2);
        unsigned long long lmax = 0ull;
        for (int i = lane; i < n; i += 64) lmax = umax64(lmax, cand[i]);

        for (int k = 0; k < TOPK; ++k) {
            unsigned long long wm = lmax;
            #pragma unroll
            for (int s = 32; s; s >>= 1) {
                unsigned long long o = (unsigned long long)__shfl_xor((long long)wm, s, 64);
                wm = umax64(wm, o);
            }
            const unsigned long long gm = wm;  // all lanes agree
            if (lane == 0) {
                const size_t bk = (size_t)bc * TOPK + k;
                const size_t nbk = (size_t)BC * TOPK;
                if (gm != 0ull) {
                    unsigned fb = (unsigned)(gm >> 32);
                    unsigned idx = 0xFFFFu - (unsigned)(gm & 0xFFFFFFFFull);
                    out[bk * 2]       = (float)((idx % WW) * 4);
                    out[bk * 2 + 1]   = (float)((idx / WW) * 4);
                    out[nbk * 2 + bk] = __uint_as_float(fb);
                    out[nbk * 3 + bk] = 1.0f;
                } else {
                    out[bk * 2] = 0.0f; out[bk * 2 + 1] = 0.0f;
                    out[nbk * 2 + bk] = 0.0f; out[nbk * 3 + bk] = 0.0f;
                }
            }
            if (gm != 0ull && lmax == gm) {
                unsigned long long nl = 0ull;
                for (int i = lane; i < n; i += 64) {
                    if (cand[i] == gm) cand[i] = 0ull;
                    nl = umax64(nl, cand[i]);
                }
                lmax = nl;
            }
        }
    }
}

extern "C" void kernel_launch(void* const* d_in, const int* in_sizes, int n_in,
                              void* d_out, int out_size, void* d_ws, size_t ws_size,
                              hipStream_t stream) {
    const float* heat = (const float*)d_in[0];
    float* out = (float*)d_out;
    const int BC = in_sizes[0] / (HH * WW);
    hipLaunchKernelGGL(pose_topk_kernel, dim3(BC), dim3(1024), 0, stream, heat, out, BC);
}

// Round 4
// 65.212 us; speedup vs baseline: 4.7846x; 1.4179x over previous
//
#include <hip/hip_runtime.h>
#include <cstdint>

#define HEAT_THRESH 0.1f
#define STATIC_T 0.998f
#define WW 256
#define HH 256
#define TOPK 30
#define NBINS 2048
#define CAP2 1024
#define BASEBITS 0x3DCCCCCDu  /* float bits of 0.1f */
#define BINSH 14
#define MAXBIN 1740           /* ((0x3F800000 - BASEBITS) >> 14) */

__device__ __forceinline__ unsigned long long umax64(unsigned long long a, unsigned long long b) {
    return a > b ? a : b;
}

__global__ __launch_bounds__(1024, 2) void pose_topk_kernel(const float* __restrict__ heat,
                                                            float* __restrict__ out, int BC) {
    const int bc = blockIdx.x;
    const float* __restrict__ hm = heat + (size_t)bc * (HH * WW);
    const int tid = threadIdx.x;
    const int lane = tid & 63;
    const int cx = lane;       // column group: columns [cx*4, cx*4+4) — wave spans full row
    const int ry = tid >> 6;   // row band: rows [ry*16, ry*16+16)  (16 bands, 1 per wave)

    __shared__ unsigned int hist[NBINS];
    __shared__ unsigned long long cand[CAP2];
    __shared__ int cnt;
    __shared__ unsigned int tbbits_s;

    hist[tid] = 0u;
    hist[tid + 1024] = 0u;
    if (tid == 0) cnt = 0;
    __syncthreads();

    const int x0 = cx * 4;
    const int y0 = ry * 16;
    const float NEG = -INFINITY;

    auto ld = [&](int y) {
        return *reinterpret_cast<const float4*>(hm + y * WW + x0);
    };
    // horizontal 3-max via wave shuffles (no halo loads)
    auto hmaxs = [&](const float4& v, float4& h) {
        float l = __shfl_up(v.w, 1u, 64);
        float r = __shfl_down(v.x, 1u, 64);
        if (cx == 0) l = NEG;
        if (cx == 63) r = NEG;
        h.x = fmaxf(fmaxf(l, v.x), v.y);
        h.y = fmaxf(fmaxf(v.x, v.y), v.z);
        h.z = fmaxf(fmaxf(v.y, v.z), v.w);
        h.w = fmaxf(fmaxf(v.z, v.w), r);
    };
    auto push = [&](float c, int idx) {
        int pos = atomicAdd(&cnt, 1);
        if (pos < CAP2) {
            unsigned long long fb = (unsigned long long)__float_as_uint(c);
            cand[pos] = (fb << 32) | (unsigned long long)(0xFFFFu - (unsigned)idx);
        }
    };

    // ---------- Pass A: NMS + histogram + static-threshold push (single stream) ----------
    {
        float4 hmA, hmB, cB;
        if (y0 > 0) { float4 v = ld(y0 - 1); hmaxs(v, hmA); }
        else hmA = make_float4(NEG, NEG, NEG, NEG);
        { cB = ld(y0); hmaxs(cB, hmB); }

        #pragma unroll
        for (int t = 0; t < 16; ++t) {
            const int y = y0 + t;
            float4 hmC, cC;
            if (y + 1 < HH) { cC = ld(y + 1); hmaxs(cC, hmC); }
            else { hmC = make_float4(NEG, NEG, NEG, NEG); cC = hmC; }
            float va0 = fmaxf(fmaxf(hmA.x, hmB.x), hmC.x);
            float va1 = fmaxf(fmaxf(hmA.y, hmB.y), hmC.y);
            float va2 = fmaxf(fmaxf(hmA.z, hmB.z), hmC.z);
            float va3 = fmaxf(fmaxf(hmA.w, hmB.w), hmC.w);
            const int ib = y * WW + x0;
            #define PROC(c, va, off)                                                             \
                if ((c) == (va) && (c) > HEAT_THRESH) {                                          \
                    atomicAdd(&hist[(__float_as_uint(c) - BASEBITS) >> BINSH], 1u);              \
                    if ((c) >= STATIC_T) push((c), ib + (off));                                  \
                }
            PROC(cB.x, va0, 0)
            PROC(cB.y, va1, 1)
            PROC(cB.z, va2, 2)
            PROC(cB.w, va3, 3)
            #undef PROC
            hmA = hmB; hmB = hmC; cB = cC;
        }
    }
    __syncthreads();

    // ---------- Threshold-bin scan (thread 0; exits in ~2-3 iters: values crowd near 1.0) ----------
    if (tid == 0) {
        unsigned cum = 0;
        int b;
        for (b = MAXBIN; b >= 0; --b) {
            cum += hist[b];
            if (cum >= TOPK) break;
        }
        if (b < 0) b = 0;
        tbbits_s = BASEBITS + ((unsigned)b << BINSH);
    }
    __syncthreads();
    const unsigned tbbits = tbbits_s;

    // ---------- Fallback rescan (block-uniform; only if top-30 boundary < STATIC_T — ~never) ----------
    if (__uint_as_float(tbbits) < STATIC_T) {
        float4 hmA, hmB, cB;
        if (y0 > 0) { float4 v = ld(y0 - 1); hmaxs(v, hmA); }
        else hmA = make_float4(NEG, NEG, NEG, NEG);
        { cB = ld(y0); hmaxs(cB, hmB); }

        #pragma unroll
        for (int t = 0; t < 16; ++t) {
            const int y = y0 + t;
            float4 hmC, cC;
            if (y + 1 < HH) { cC = ld(y + 1); hmaxs(cC, hmC); }
            else { hmC = make_float4(NEG, NEG, NEG, NEG); cC = hmC; }
            float va0 = fmaxf(fmaxf(hmA.x, hmB.x), hmC.x);
            float va1 = fmaxf(fmaxf(hmA.y, hmB.y), hmC.y);
            float va2 = fmaxf(fmaxf(hmA.z, hmB.z), hmC.z);
            float va3 = fmaxf(fmaxf(hmA.w, hmB.w), hmC.w);
            const int ib = y * WW + x0;
            #define PROCF(c, va, off)                                                            \
                if ((c) == (va) && (c) > HEAT_THRESH && (c) < STATIC_T &&                        \
                    __float_as_uint(c) >= tbbits) {                                              \
                    push((c), ib + (off));                                                       \
                }
            PROCF(cB.x, va0, 0)
            PROCF(cB.y, va1, 1)
            PROCF(cB.z, va2, 2)
            PROCF(cB.w, va3, 3)
            #undef PROCF
            hmA = hmB; hmB = hmC; cB = cC;
        }
    }
    __syncthreads();

    // ---------- Single-wave top-30 selection (no barriers) ----------
    if (tid < 64) {
        const int n = min(cnt, CAP2);
        unsigned long long lmax = 0ull;
        for (int i = lane; i < n; i += 64) lmax = umax64(lmax, cand[i]);

        for (int k = 0; k < TOPK; ++k) {
            unsigned long long wm = lmax;
            #pragma unroll
            for (int s = 32; s; s >>= 1) {
                unsigned long long o = (unsigned long long)__shfl_xor((long long)wm, s, 64);
                wm = umax64(wm, o);
            }
            const unsigned long long gm = wm;  // all lanes agree
            if (lane == 0) {
                const size_t bk = (size_t)bc * TOPK + k;
                const size_t nbk = (size_t)BC * TOPK;
                if (gm != 0ull) {
                    unsigned fb = (unsigned)(gm >> 32);
                    unsigned idx = 0xFFFFu - (unsigned)(gm & 0xFFFFFFFFull);
                    out[bk * 2]       = (float)((idx % WW) * 4);
                    out[bk * 2 + 1]   = (float)((idx / WW) * 4);
                    out[nbk * 2 + bk] = __uint_as_float(fb);
                    out[nbk * 3 + bk] = 1.0f;
                } else {
                    out[bk * 2] = 0.0f; out[bk * 2 + 1] = 0.0f;
                    out[nbk * 2 + bk] = 0.0f; out[nbk * 3 + bk] = 0.0f;
                }
            }
            if (gm != 0ull && lmax == gm) {
                unsigned long long nl = 0ull;
                for (int i = lane; i < n; i += 64) {
                    if (cand[i] == gm) cand[i] = 0ull;
                    nl = umax64(nl, cand[i]);
                }
                lmax = nl;
            }
        }
    }
}

extern "C" void kernel_launch(void* const* d_in, const int* in_sizes, int n_in,
                              void* d_out, int out_size, void* d_ws, size_t ws_size,
                              hipStream_t stream) {
    const float* heat = (const float*)d_in[0];
    float* out = (float*)d_out;
    const int BC = in_sizes[0] / (HH * WW);
    hipLaunchKernelGGL(pose_topk_kernel, dim3(BC), dim3(1024), 0, stream, heat, out, BC);
}